// Round 6
// baseline (334.157 us; speedup 1.0000x reference)
//
#include <hip/hip_runtime.h>

// SNN: B=4096, T=784, H=128, OUT=10.  1 wave/block (1024 blocks = 1 wave/SIMD),
// 4 batches/wave, 16 lanes/batch (= one DPP row), 8 h/lane.
// ZERO LDS: the 16-lane reduction of the 10 layer-2 partials is a 4-stage
// DPP butterfly on the VALU pipe (R4 showed the LDS pipe saturated: 4 waves/CU
// x 26 ds ops/step ~ 600 cyc/step of shared-pipe time, VALUBusy stuck at 48%).
// After the butterfly every lane has all 10 sums; lane l16==o selects sum[o]
// via a hoisted cndmask chain and runs LIF2 for output o itself.

#define T_STEPS 784
#define T4      196
#define HID     128
#define NOUT    10
#define TSTART  522   // T*2//3

// v + value-from-lane(CTRL) within the 16-lane DPP row; folds to v_add_f32_dpp.
template<int CTRL>
__device__ __forceinline__ float dpp_add(float v) {
    union { float f; int i; } u, r;
    u.f = v;
    r.i = __builtin_amdgcn_update_dpp(0, u.i, CTRL, 0xF, 0xF, true);
    return v + r.f;
}

__global__ __launch_bounds__(64, 1)
void snn_kernel(const float* __restrict__ x,    // [B, T]
                const float* __restrict__ W1,   // [H]
                const float* __restrict__ b1,   // [H]
                const float* __restrict__ W2,   // [OUT, H]
                const float* __restrict__ b2,   // [OUT]
                float* __restrict__ out)        // [B, OUT]
{
    const int tid   = threadIdx.x;
    const int l16   = tid & 15;
    const int batch = blockIdx.x * 4 + (tid >> 4);
    const int h0    = l16 * 8;

    // ---- weights in registers ----
    float w1v[8], b1v[8], w2v[NOUT][8];
#pragma unroll
    for (int j = 0; j < 8; ++j) { w1v[j] = W1[h0 + j]; b1v[j] = b1[h0 + j]; }
#pragma unroll
    for (int o = 0; o < NOUT; ++o)
#pragma unroll
        for (int j = 0; j < 8; ++j) w2v[o][j] = W2[o * HID + h0 + j];

    float v1[8];
#pragma unroll
    for (int j = 0; j < 8; ++j) v1[j] = 0.0f;

    const float b2v = (l16 < NOUT) ? b2[l16] : 0.0f;
    float v2 = 0.0f, outacc = 0.0f;

    // hoisted lane-select masks (SGPR pairs, reused by 9 cndmask per step)
    const bool e1 = (l16 == 1), e2 = (l16 == 2), e3 = (l16 == 3),
               e4 = (l16 == 4), e5 = (l16 == 5), e6 = (l16 == 6),
               e7 = (l16 == 7), e8 = (l16 == 8), e9 = (l16 == 9);

    const float4* xrow = reinterpret_cast<const float4*>(x + (size_t)batch * T_STEPS);
    float4 xc = xrow[0];

    for (int t4 = 0; t4 < T4; ++t4) {
        float4 xn = xrow[(t4 + 1 < T4) ? (t4 + 1) : t4];   // prefetch next 4 steps
        const float xs[4] = {xc.x, xc.y, xc.z, xc.w};

#pragma unroll
        for (int u = 0; u < 4; ++u) {
            const float xv = xs[u];
            float acc[NOUT];

            // ---- phase A: LIF1 + partial dot over this lane's 8 h ----
            {
                float h1 = fmaf(xv, w1v[0], b1v[0]);
                float d  = h1 - v1[0];
                float vn = fmaf(d, 0.5f, v1[0]);
                bool  s  = (vn >= 1.0f);
                float sf = s ? 1.0f : 0.0f;
                v1[0]    = s ? 0.0f : vn;
#pragma unroll
                for (int o = 0; o < NOUT; ++o) acc[o] = sf * w2v[o][0];
            }
#pragma unroll
            for (int j = 1; j < 8; ++j) {
                float h1 = fmaf(xv, w1v[j], b1v[j]);
                float d  = h1 - v1[j];
                float vn = fmaf(d, 0.5f, v1[j]);
                bool  s  = (vn >= 1.0f);
                float sf = s ? 1.0f : 0.0f;
                v1[j]    = s ? 0.0f : vn;
#pragma unroll
                for (int o = 0; o < NOUT; ++o) acc[o] = fmaf(sf, w2v[o][j], acc[o]);
            }

            // ---- 16-lane butterfly per output (VALU pipe, within DPP row) ----
#pragma unroll
            for (int o = 0; o < NOUT; ++o) {
                float s = acc[o];
                s = dpp_add<0xB1>(s);    // quad_perm [1,0,3,2] : + lane^1
                s = dpp_add<0x4E>(s);    // quad_perm [2,3,0,1] : + lane^2 pair
                s = dpp_add<0x141>(s);   // row_half_mirror    : + other quad
                s = dpp_add<0x140>(s);   // row_mirror         : + other half
                acc[o] = s;              // all 16 lanes now hold total for o
            }

            // ---- lane l16==o takes sum[o]; LIF2; spike count ----
            float h2 = acc[0];
            h2 = e1 ? acc[1] : h2;  h2 = e2 ? acc[2] : h2;  h2 = e3 ? acc[3] : h2;
            h2 = e4 ? acc[4] : h2;  h2 = e5 ? acc[5] : h2;  h2 = e6 ? acc[6] : h2;
            h2 = e7 ? acc[7] : h2;  h2 = e8 ? acc[8] : h2;  h2 = e9 ? acc[9] : h2;
            h2 += b2v;

            float d2  = h2 - v2;
            float v2n = fmaf(d2, 0.5f, v2);
            bool  sp  = (v2n >= 1.0f);
            v2 = sp ? 0.0f : v2n;
            const int t = t4 * 4 + u;
            outacc += (sp && (t >= TSTART)) ? 1.0f : 0.0f;
        }
        xc = xn;
    }

    if (l16 < NOUT) out[batch * NOUT + l16] = outacc;
}

extern "C" void kernel_launch(void* const* d_in, const int* in_sizes, int n_in,
                              void* d_out, int out_size, void* d_ws, size_t ws_size,
                              hipStream_t stream)
{
    const float* x  = (const float*)d_in[0];
    const float* W1 = (const float*)d_in[1];
    const float* b1 = (const float*)d_in[2];
    const float* W2 = (const float*)d_in[3];
    const float* b2 = (const float*)d_in[4];
    float* out = (float*)d_out;

    snn_kernel<<<dim3(1024), dim3(64), 0, stream>>>(x, W1, b1, W2, b2, out);
}

// Round 7
// 282.934 us; speedup vs baseline: 1.1810x; 1.1810x over previous
//
#include <hip/hip_runtime.h>

// SNN: B=4096, T=784, H=128, OUT=10.  1 wave/block (1024 blocks = 1/SIMD),
// 4 batches/wave, 16 lanes/batch (one DPP row), 8 h/lane.
// VALU-issue-bound (R6: 79.6% VALUBusy, ~347 instr/step). This round:
//  - packed fp32 (v_pk_fma_f32) phase A: LIF1 + s1*W2 dot on float2 lanes
//  - inline-asm v_add_f32_dpp butterfly, quad-renamed (sigma={0,5,5,0}) so
//    cross-quad stages need only 5+5 instrs; select = 4 cndmask w/ ballot
//    masks hoisted to SGPR pairs.
// Layer-1 math bit-identical to prior passing rounds (same fmaf per element);
// only h2's reduction tree reorders (validated tolerant: margin >> ulp).

#define T_STEPS 784
#define T4      196
#define HID     128
#define NOUT    10
#define TSTART  522   // T*2//3

typedef float f2 __attribute__((ext_vector_type(2)));

// d = dpp(a) + b variants (fused single v_add_f32_dpp, all rows/banks on)
__device__ __forceinline__ float add_qp1(float a) {
    float d;
    asm("v_add_f32_dpp %0, %1, %2 quad_perm:[1,0,3,2] row_mask:0xf bank_mask:0xf"
        : "=v"(d) : "v"(a), "v"(a));
    return d;                       // + lane^1 (within quad)
}
__device__ __forceinline__ float add_qp2(float a) {
    float d;
    asm("v_add_f32_dpp %0, %1, %2 quad_perm:[2,3,0,1] row_mask:0xf bank_mask:0xf"
        : "=v"(d) : "v"(a), "v"(a));
    return d;                       // + lane^2 -> quad sums
}
__device__ __forceinline__ float add_hm(float a, float b) {
    float d;
    asm("v_add_f32_dpp %0, %1, %2 row_half_mirror row_mask:0xf bank_mask:0xf"
        : "=v"(d) : "v"(a), "v"(b));
    return d;                       // d = other-quad(a) + b (within 8)
}
__device__ __forceinline__ float add_mir(float a) {
    float d;
    asm("v_add_f32_dpp %0, %1, %2 row_mirror row_mask:0xf bank_mask:0xf"
        : "=v"(d) : "v"(a), "v"(a));
    return d;                       // + other half (within 16)
}
// d = m[lane] ? t : f   (mask is a loop-invariant SGPR pair)
__device__ __forceinline__ float sel(float f, float t, unsigned long long m) {
    float d;
    asm("v_cndmask_b32 %0, %1, %2, %3" : "=v"(d) : "v"(f), "v"(t), "s"(m));
    return d;
}

__global__ __launch_bounds__(64, 1)
void snn_kernel(const float* __restrict__ x,    // [B, T]
                const float* __restrict__ W1,   // [H]
                const float* __restrict__ b1,   // [H]
                const float* __restrict__ W2,   // [OUT, H]
                const float* __restrict__ b2,   // [OUT]
                float* __restrict__ out)        // [B, OUT]
{
    const int tid   = threadIdx.x;
    const int l16   = tid & 15;
    const int q     = l16 >> 2;       // quad within the 16-lane row
    const int p     = l16 & 3;        // position within quad
    const int batch = blockIdx.x * 4 + (tid >> 4);
    const int h0    = l16 * 8;

    // per-quad output renaming: reg r holds output (r + sig) % 10
    const int sig = (q == 1 || q == 2) ? 5 : 0;

    // ---- weights in registers (packed pairs j = 2k, 2k+1) ----
    f2 w1p[4], b1p[4], v1p[4], w2p[NOUT][4];
    {
        const f2* w1v = reinterpret_cast<const f2*>(W1 + h0);
        const f2* b1v = reinterpret_cast<const f2*>(b1 + h0);
#pragma unroll
        for (int k = 0; k < 4; ++k) { w1p[k] = w1v[k]; b1p[k] = b1v[k]; v1p[k] = f2{0.f, 0.f}; }
#pragma unroll
        for (int r = 0; r < NOUT; ++r) {
            int row = r + sig; if (row >= NOUT) row -= NOUT;
            const f2* wr = reinterpret_cast<const f2*>(W2 + row * HID + h0);
#pragma unroll
            for (int k = 0; k < 4; ++k) w2p[r][k] = wr[k];
        }
    }

    // ---- lane roles after the renamed reduce ----
    // quad0: d[p]   = out p      quad1: d[p] = out p+5
    // quad2: d[4]   = out 9 (p==0)   quad3: d[4] = out 4 (p==0)
    int  oidx;  bool active;
    if      (q == 0) { oidx = p;     active = true;      }
    else if (q == 1) { oidx = p + 5; active = true;      }
    else if (q == 2) { oidx = 9;     active = (p == 0);  }
    else             { oidx = 4;     active = (p == 0);  }
    const float b2v = active ? b2[oidx] : 0.0f;

    // select-tree masks (wave-uniform -> SGPR pairs, loop-invariant)
    const unsigned long long mb0 = __ballot(p & 1);
    const unsigned long long mb1 = __ballot(p & 2);
    const unsigned long long mb2 = __ballot(q >= 2);

    float v2 = 0.0f, outacc = 0.0f;
    const f2 half2 = {0.5f, 0.5f};

    const float4* xrow = reinterpret_cast<const float4*>(x + (size_t)batch * T_STEPS);
    float4 xc = xrow[0];

    // ---- one timestep ----
    auto step = [&](float xv, int tstep) {
        const f2 xp = {xv, xv};
        f2 acc[NOUT];

        // phase A: LIF1 (packed, bit-identical per element) + partial dot
#pragma unroll
        for (int k = 0; k < 4; ++k) {
            f2 h1 = __builtin_elementwise_fma(xp, w1p[k], b1p[k]);
            f2 dd = h1 - v1p[k];
            f2 vn = __builtin_elementwise_fma(dd, half2, v1p[k]);
            bool sa = vn.x >= 1.0f, sb = vn.y >= 1.0f;
            f2 sf;
            sf.x = sa ? 1.0f : 0.0f;  sf.y = sb ? 1.0f : 0.0f;
            v1p[k].x = sa ? 0.0f : vn.x;  v1p[k].y = sb ? 0.0f : vn.y;
            if (k == 0) {
#pragma unroll
                for (int r = 0; r < NOUT; ++r) acc[r] = sf * w2p[r][0];
            } else {
#pragma unroll
                for (int r = 0; r < NOUT; ++r)
                    acc[r] = __builtin_elementwise_fma(sf, w2p[r][k], acc[r]);
            }
        }

        // combine packed halves -> 10 lane partials
        float t[NOUT];
#pragma unroll
        for (int r = 0; r < NOUT; ++r) t[r] = acc[r].x + acc[r].y;

        // butterfly stages 1-2: quad sums (all 10 regs)
#pragma unroll
        for (int r = 0; r < NOUT; ++r) t[r] = add_qp1(t[r]);
#pragma unroll
        for (int r = 0; r < NOUT; ++r) t[r] = add_qp2(t[r]);

        // stage 3: cross-quad within 8, reg offset +5 (renaming makes outputs line up)
        float d5[5];
#pragma unroll
        for (int r = 0; r < 5; ++r) d5[r] = add_hm(t[r + 5], t[r]);
        // stage 4: cross-half, same reg both sides
#pragma unroll
        for (int r = 0; r < 5; ++r) d5[r] = add_mir(d5[r]);
        // now: quad0 lanes: d5[r]=out r;  quad1: out r+5;  quad2: out r+5;  quad3: out r

        // select this lane's output: k = p (quads 0,1) else 4
        float s01  = sel(d5[0], d5[1], mb0);
        float s23  = sel(d5[2], d5[3], mb0);
        float s03  = sel(s01, s23, mb1);
        float hsel = sel(s03, d5[4], mb2);

        // LIF2 + spike count
        float h2  = hsel + b2v;
        float d2  = h2 - v2;
        float v2n = fmaf(d2, 0.5f, v2);
        bool  sp  = (v2n >= 1.0f);
        v2 = sp ? 0.0f : v2n;
        outacc += (sp && tstep >= TSTART) ? 1.0f : 0.0f;
    };

    for (int t4 = 0; t4 < T4; ++t4) {
        float4 xn = xrow[(t4 + 1 < T4) ? (t4 + 1) : t4];   // prefetch next 4 steps
        const int s0i = t4 * 4;
        step(xc.x, s0i);
        step(xc.y, s0i + 1);
        step(xc.z, s0i + 2);
        step(xc.w, s0i + 3);
        xc = xn;
    }

    if (active) out[batch * NOUT + oidx] = outacc;
}

extern "C" void kernel_launch(void* const* d_in, const int* in_sizes, int n_in,
                              void* d_out, int out_size, void* d_ws, size_t ws_size,
                              hipStream_t stream)
{
    const float* x  = (const float*)d_in[0];
    const float* W1 = (const float*)d_in[1];
    const float* b1 = (const float*)d_in[2];
    const float* W2 = (const float*)d_in[3];
    const float* b2 = (const float*)d_in[4];
    float* out = (float*)d_out;

    snn_kernel<<<dim3(1024), dim3(64), 0, stream>>>(x, W1, b1, W2, b2, out);
}

// Round 8
// 282.389 us; speedup vs baseline: 1.1833x; 1.0019x over previous
//
#include <hip/hip_runtime.h>

// SNN: B=4096, T=784, H=128, OUT=10.  1 wave/block (1024 blocks = 1/SIMD),
// 4 batches/wave, 16 lanes/batch (one DPP row), 8 h/lane.
// R7 post-mortem: VGPR_Count=88 but the design needs ~104 for weights alone
// -> compiler was re-loading W1/b1/W2 from L1 every step (the ~130 extra
// instrs + 205 idle cyc/step). R8:
//  (1) pin all weights in VGPRs via empty asm "+v" barriers (no remat),
//  (2) force v_pk_fma_f32/v_pk_mul_f32 via inline asm (bit-identical per elem),
//  (3) software-pipeline in-register: reduce+LIF2(s-1) interleaved under
//      phaseA(s) -> DPP sources are >=20 instr old (no hazard nops).
// Reduce structure (quad-renamed butterfly + sel tree) is IDENTICAL to the
// R7 kernel that passed with absmax=0.

#define T_STEPS 784
#define T4      196
#define HID     128
#define NOUT    10
#define TSTART  522   // T*2//3

typedef float f2 __attribute__((ext_vector_type(2)));

// ---- packed f32 (VOP3P, register pairs); per-element bit-identical to fmaf ----
__device__ __forceinline__ f2 pk_fma(f2 a, f2 b, f2 c) {
    f2 d;
    asm("v_pk_fma_f32 %0, %1, %2, %3" : "=v"(d) : "v"(a), "v"(b), "v"(c));
    return d;
}
__device__ __forceinline__ f2 pk_mul(f2 a, f2 b) {
    f2 d;
    asm("v_pk_mul_f32 %0, %1, %2" : "=v"(d) : "v"(a), "v"(b));
    return d;
}

// ---- DPP cross-lane adds (fused, all rows/banks) ----
__device__ __forceinline__ float add_qp1(float a) {
    float d;
    asm("v_add_f32_dpp %0, %1, %2 quad_perm:[1,0,3,2] row_mask:0xf bank_mask:0xf"
        : "=v"(d) : "v"(a), "v"(a));
    return d;
}
__device__ __forceinline__ float add_qp2(float a) {
    float d;
    asm("v_add_f32_dpp %0, %1, %2 quad_perm:[2,3,0,1] row_mask:0xf bank_mask:0xf"
        : "=v"(d) : "v"(a), "v"(a));
    return d;
}
__device__ __forceinline__ float add_hm(float a, float b) {
    float d;
    asm("v_add_f32_dpp %0, %1, %2 row_half_mirror row_mask:0xf bank_mask:0xf"
        : "=v"(d) : "v"(a), "v"(b));
    return d;
}
__device__ __forceinline__ float add_mir(float a) {
    float d;
    asm("v_add_f32_dpp %0, %1, %2 row_mirror row_mask:0xf bank_mask:0xf"
        : "=v"(d) : "v"(a), "v"(a));
    return d;
}
__device__ __forceinline__ float sel(float f, float t, unsigned long long m) {
    float d;
    asm("v_cndmask_b32 %0, %1, %2, %3" : "=v"(d) : "v"(f), "v"(t), "s"(m));
    return d;
}

// ---- phase A chunk K (LIF1 on h-pair K + dot partial for 10 outputs) ----
#define PHASEA_K(K)                                                          \
    {                                                                        \
        f2 h1 = pk_fma(xp, w1p[K], b1p[K]);                                  \
        f2 dd = pk_fma(v1p[K], negone, h1);      /* = h1 - v1 (1 rounding) */\
        f2 vn = pk_fma(dd, halfs, v1p[K]);                                   \
        bool sa = vn.x >= 1.0f, sb = vn.y >= 1.0f;                           \
        f2 sf;                                                               \
        sf.x = sa ? 1.0f : 0.0f;  sf.y = sb ? 1.0f : 0.0f;                   \
        v1p[K].x = sa ? 0.0f : vn.x;  v1p[K].y = sb ? 0.0f : vn.y;           \
        _Pragma("unroll")                                                    \
        for (int r = 0; r < NOUT; ++r)                                       \
            acc[r] = (K == 0) ? pk_mul(sf, w2p[r][0])                        \
                              : pk_fma(sf, w2p[r][K], acc[r]);               \
    }

__global__ __launch_bounds__(64, 1)
void snn_kernel(const float* __restrict__ x,    // [B, T]
                const float* __restrict__ W1,   // [H]
                const float* __restrict__ b1,   // [H]
                const float* __restrict__ W2,   // [OUT, H]
                const float* __restrict__ b2,   // [OUT]
                float* __restrict__ out)        // [B, OUT]
{
    const int tid   = threadIdx.x;
    const int l16   = tid & 15;
    const int q     = l16 >> 2;
    const int p     = l16 & 3;
    const int batch = blockIdx.x * 4 + (tid >> 4);
    const int h0    = l16 * 8;

    const int sig = (q == 1 || q == 2) ? 5 : 0;   // per-quad output renaming

    // ---- load weights, then PIN them (opaque asm def: no rematerialization) ----
    f2 w1p[4], b1p[4], v1p[4], w2p[NOUT][4];
    {
        const f2* w1v = reinterpret_cast<const f2*>(W1 + h0);
        const f2* b1v = reinterpret_cast<const f2*>(b1 + h0);
#pragma unroll
        for (int k = 0; k < 4; ++k) { w1p[k] = w1v[k]; b1p[k] = b1v[k]; v1p[k] = f2{0.f, 0.f}; }
#pragma unroll
        for (int r = 0; r < NOUT; ++r) {
            int row = r + sig; if (row >= NOUT) row -= NOUT;
            const f2* wr = reinterpret_cast<const f2*>(W2 + row * HID + h0);
#pragma unroll
            for (int k = 0; k < 4; ++k) w2p[r][k] = wr[k];
        }
#pragma unroll
        for (int k = 0; k < 4; ++k) { asm("" : "+v"(w1p[k])); asm("" : "+v"(b1p[k])); }
#pragma unroll
        for (int r = 0; r < NOUT; ++r)
#pragma unroll
            for (int k = 0; k < 4; ++k) asm("" : "+v"(w2p[r][k]));
    }

    // ---- lane roles after the renamed reduce (same as R7-passed kernel) ----
    int  oidx;  bool active;
    if      (q == 0) { oidx = p;     active = true;     }
    else if (q == 1) { oidx = p + 5; active = true;     }
    else if (q == 2) { oidx = 9;     active = (p == 0); }
    else             { oidx = 4;     active = (p == 0); }
    const float b2v = active ? b2[oidx] : 0.0f;

    const unsigned long long mb0 = __ballot(p & 1);
    const unsigned long long mb1 = __ballot(p & 2);
    const unsigned long long mb2 = __ballot(q >= 2);

    float v2 = 0.0f, outacc = 0.0f;
    const f2 halfs  = { 0.5f,  0.5f};
    const f2 negone = {-1.0f, -1.0f};

    float tp[NOUT];   // post-combine partials of the PREVIOUS step

    const float4* xrow = reinterpret_cast<const float4*>(x + (size_t)batch * T_STEPS);
    float4 xc = xrow[0];

    // ---- prologue: phase A of step 0 only ----
    {
        const f2 xp = {xc.x, xc.x};
        f2 acc[NOUT];
        PHASEA_K(0) PHASEA_K(1) PHASEA_K(2) PHASEA_K(3)
#pragma unroll
        for (int r = 0; r < NOUT; ++r) tp[r] = acc[r].x + acc[r].y;
    }

    // ---- pipelined step: reduce+LIF2(s-1) interleaved with phaseA(s) ----
#define STEP(XV, SPREV)                                                       \
    {                                                                         \
        const f2 xp = {(XV), (XV)};                                           \
        f2 acc[NOUT];                                                         \
        float r1[NOUT], r2[NOUT], d5[5];                                      \
        _Pragma("unroll") for (int r = 0; r < NOUT; ++r) r1[r] = add_qp1(tp[r]); \
        PHASEA_K(0)                                                           \
        _Pragma("unroll") for (int r = 0; r < NOUT; ++r) r2[r] = add_qp2(r1[r]); \
        PHASEA_K(1)                                                           \
        _Pragma("unroll") for (int r = 0; r < 5; ++r) d5[r] = add_hm(r2[r + 5], r2[r]); \
        PHASEA_K(2)                                                           \
        _Pragma("unroll") for (int r = 0; r < 5; ++r) d5[r] = add_mir(d5[r]); \
        PHASEA_K(3)                                                           \
        float s01  = sel(d5[0], d5[1], mb0);                                  \
        float s23  = sel(d5[2], d5[3], mb0);                                  \
        float s03  = sel(s01, s23, mb1);                                      \
        float hsel = sel(s03, d5[4], mb2);                                    \
        float h2   = hsel + b2v;                                              \
        float dlt  = h2 - v2;                                                 \
        float v2n  = fmaf(dlt, 0.5f, v2);                                     \
        bool  sp   = (v2n >= 1.0f);                                           \
        v2 = sp ? 0.0f : v2n;                                                 \
        outacc += (sp && (SPREV) >= TSTART) ? 1.0f : 0.0f;                    \
        _Pragma("unroll") for (int r = 0; r < NOUT; ++r) tp[r] = acc[r].x + acc[r].y; \
    }

    // t4 = 0: steps 1..3 (step 0 phase A done above)
    {
        float4 xn = xrow[1];
        STEP(xc.y, 0) STEP(xc.z, 1) STEP(xc.w, 2)
        xc = xn;
    }
    for (int t4 = 1; t4 < T4; ++t4) {
        float4 xn = xrow[(t4 + 1 < T4) ? (t4 + 1) : t4];
        const int s0i = t4 * 4;
        STEP(xc.x, s0i - 1) STEP(xc.y, s0i) STEP(xc.z, s0i + 1) STEP(xc.w, s0i + 2)
        xc = xn;
    }

    // ---- epilogue: reduce+LIF2 for step 783 ----
    {
        float r1[NOUT], r2[NOUT], d5[5];
#pragma unroll
        for (int r = 0; r < NOUT; ++r) r1[r] = add_qp1(tp[r]);
#pragma unroll
        for (int r = 0; r < NOUT; ++r) r2[r] = add_qp2(r1[r]);
#pragma unroll
        for (int r = 0; r < 5; ++r) d5[r] = add_hm(r2[r + 5], r2[r]);
#pragma unroll
        for (int r = 0; r < 5; ++r) d5[r] = add_mir(d5[r]);
        float s01  = sel(d5[0], d5[1], mb0);
        float s23  = sel(d5[2], d5[3], mb0);
        float s03  = sel(s01, s23, mb1);
        float hsel = sel(s03, d5[4], mb2);
        float h2   = hsel + b2v;
        float dlt  = h2 - v2;
        float v2n  = fmaf(dlt, 0.5f, v2);
        bool  sp   = (v2n >= 1.0f);
        outacc += sp ? 1.0f : 0.0f;   // step 783 >= TSTART always
    }

    if (active) out[batch * NOUT + oidx] = outacc;
}

extern "C" void kernel_launch(void* const* d_in, const int* in_sizes, int n_in,
                              void* d_out, int out_size, void* d_ws, size_t ws_size,
                              hipStream_t stream)
{
    const float* x  = (const float*)d_in[0];
    const float* W1 = (const float*)d_in[1];
    const float* b1 = (const float*)d_in[2];
    const float* W2 = (const float*)d_in[3];
    const float* b2 = (const float*)d_in[4];
    float* out = (float*)d_out;

    snn_kernel<<<dim3(1024), dim3(64), 0, stream>>>(x, W1, b1, W2, b2, out);
}